// Round 2
// baseline (1377.830 us; speedup 1.0000x reference)
//
#include <hip/hip_runtime.h>
#include <cstdint>

#define C_ 256
#define H_ 96
#define W_ 160
#define TH 16
#define TW 32
#define PP 8
#define GROUPS 64            // (TH*TW)/PP
#define NTHR 576             // GROUPS * 9
#define CCH 4                // channels per chunk
#define NCH 64               // C_/CCH
#define S1STR 36             // padded row stride (words), tile row = 32
#define S2H 24               // TH + 8
#define S2W 40               // TW + 8
#define S2STR 44             // padded row stride (words)
#define S1CH (TH*S1STR)      // 576 words per channel
#define S2CH (S2H*S2STR)     // 1056 words per channel
#define S1BUF (CCH*S1CH)     // 2304
#define S2BUF (CCH*S2CH)     // 4224
#define BUFSZ (S1BUF+S2BUF)  // 6528 words
#define NF4 1472             // float4s staged per chunk: 4*128 + 4*240
#define NSTG 3
#define CHSTRIDE (CCH*H_*W_) // 61440 floats

// __launch_bounds__(576, 4): min 4 waves/EU -> VGPR cap 512/4 = 128.
// Default heuristic allocated only 84 VGPRs and spilled acc[9][8] to
// scratch (R1: WRITE_SIZE 820 MB vs 40 MB output). 16 waves/CU still
// admits the 9-wave block.
__global__ __launch_bounds__(NTHR, 4) void corr_kernel(
    const float* __restrict__ d1, const float* __restrict__ d2,
    float* __restrict__ out)
{
  __shared__ float sm[2*BUFSZ];   // 52,224 B
  const int tid = threadIdx.x;
  const int n  = blockIdx.z;
  const int y0 = blockIdx.y * TH;
  const int x0 = blockIdx.x * TW;

  // ---- staging precompute (per-thread constant across chunks) ----
  const float* gptr[NSTG];  // global source pointer (chunk 0)
  int   loff[NSTG];         // LDS word offset within buffer
  bool  pred[NSTG];         // issue the global load
  bool  wr[NSTG];           // issue the LDS write
  #pragma unroll
  for (int i = 0; i < NSTG; ++i) {
    int idx = tid + i*NTHR;
    bool valid = idx < NF4;
    bool inb = false; int go = 0, lo = 0; const float* sp = d1;
    if (idx < 512) {                 // data1 tile: 4c * 16r * 8 f4
      int c = idx >> 7, rem = idx & 127, r = rem >> 3, j = rem & 7;
      go = ((n*C_ + c)*H_ + (y0 + r))*W_ + (x0 + 4*j);
      lo = c*S1CH + r*S1STR + 4*j;
      inb = true; sp = d1;
    } else {                         // data2 halo tile: 4c * 24r * 10 f4
      int t = idx - 512;
      int c = t/240, rem = t%240, ry = rem/10, j = rem%10;
      int gy = y0 - 4 + ry, gx = x0 - 4 + 4*j;
      inb = (gy >= 0) & (gy < H_) & (gx >= 0) & (gx < W_); // f4 fully in or out
      go = ((n*C_ + c)*H_ + gy)*W_ + gx;
      lo = S1BUF + c*S2CH + ry*S2STR + 4*j;
      sp = d2;
    }
    gptr[i] = sp + go;
    loff[i] = lo;
    pred[i] = valid && inb;
    wr[i]   = valid;
  }

  float acc[9][PP];
  #pragma unroll
  for (int dx = 0; dx < 9; ++dx)
    #pragma unroll
    for (int p = 0; p < PP; ++p) acc[dx][p] = 0.f;

  const int g   = tid & (GROUPS-1);
  const int dy  = tid >> 6;          // 0..8, wave-uniform
  const int r   = g >> 2;            // tile row 0..15
  const int gx0 = (g & 3)*PP;        // tile col 0,8,16,24
  const int l1  = r*S1STR + gx0;
  const int l2  = S1BUF + (r + dy)*S2STR + gx0;

  float4 st[NSTG];

  auto load_chunk = [&](int k) {
    #pragma unroll
    for (int i = 0; i < NSTG; ++i) {
      float4 v = {0.f, 0.f, 0.f, 0.f};
      if (pred[i]) v = *(const float4*)(gptr[i] + (size_t)k*CHSTRIDE);
      st[i] = v;
    }
  };
  auto store_chunk = [&](int b) {
    float* dst = sm + b*BUFSZ;
    #pragma unroll
    for (int i = 0; i < NSTG; ++i)
      if (wr[i]) *(float4*)(dst + loff[i]) = st[i];
  };
  auto compute = [&](int b) {
    const float* base = sm + b*BUFSZ;
    #pragma unroll
    for (int c = 0; c < CCH; ++c) {
      const float* p1 = base + c*S1CH + l1;
      float4 A0 = *(const float4*)(p1);
      float4 A1 = *(const float4*)(p1 + 4);
      const float* p2 = base + c*S2CH + l2;
      float4 B0 = *(const float4*)(p2);
      float4 B1 = *(const float4*)(p2 + 4);
      float4 B2 = *(const float4*)(p2 + 8);
      float4 B3 = *(const float4*)(p2 + 12);
      float a1[8]  = {A0.x,A0.y,A0.z,A0.w,A1.x,A1.y,A1.z,A1.w};
      float a2[16] = {B0.x,B0.y,B0.z,B0.w,B1.x,B1.y,B1.z,B1.w,
                      B2.x,B2.y,B2.z,B2.w,B3.x,B3.y,B3.z,B3.w};
      #pragma unroll
      for (int dx = 0; dx < 9; ++dx)
        #pragma unroll
        for (int p = 0; p < PP; ++p)
          acc[dx][p] = fmaf(a1[p], a2[p+dx], acc[dx][p]);
    }
  };

  // ---- double-buffered main loop ----
  load_chunk(0);
  store_chunk(0);
  __syncthreads();
  #pragma unroll 1
  for (int k = 0; k < NCH-1; ++k) {
    load_chunk(k+1);        // global loads in flight during compute
    compute(k & 1);
    __syncthreads();        // all waves done reading buf[k&1]
    store_chunk((k+1) & 1);
    __syncthreads();        // writes visible
  }
  compute((NCH-1) & 1);

  // ---- epilogue ----
  const float scale = 1.0f/256.0f;
  const int y  = y0 + r;
  const int xb = x0 + gx0;
  #pragma unroll
  for (int dx = 0; dx < 9; ++dx) {
    int q = dy*9 + dx;
    size_t o = (((size_t)n*81 + q)*H_ + y)*W_ + xb;
    float4 lo4 = make_float4(acc[dx][0]*scale, acc[dx][1]*scale,
                             acc[dx][2]*scale, acc[dx][3]*scale);
    float4 hi4 = make_float4(acc[dx][4]*scale, acc[dx][5]*scale,
                             acc[dx][6]*scale, acc[dx][7]*scale);
    *(float4*)(out + o)     = lo4;
    *(float4*)(out + o + 4) = hi4;
  }
}

extern "C" void kernel_launch(void* const* d_in, const int* in_sizes, int n_in,
                              void* d_out, int out_size, void* d_ws, size_t ws_size,
                              hipStream_t stream) {
  const float* d1 = (const float*)d_in[0];
  const float* d2 = (const float*)d_in[1];
  float* out = (float*)d_out;
  dim3 grid(W_/TW, H_/TH, 8);  // 5 x 6 x 8 = 240 blocks
  corr_kernel<<<grid, NTHR, 0, stream>>>(d1, d2, out);
}

// Round 3
// 669.325 us; speedup vs baseline: 2.0585x; 2.0585x over previous
//
#include <hip/hip_runtime.h>
#include <cstdint>

#define C_ 256
#define H_ 96
#define W_ 160
#define TH 16
#define TW 32
#define PP 8
#define GROUPS 64            // (TH*TW)/PP
#define NTHR 576             // GROUPS * 9
#define CCH 4                // channels per chunk
#define NCH 64               // C_/CCH
#define S1STR 36             // padded row stride (words), tile row = 32
#define S2H 24               // TH + 8
#define S2W 40               // TW + 8
#define S2STR 44             // padded row stride (words)
#define S1CH (TH*S1STR)      // 576 words per channel
#define S2CH (S2H*S2STR)     // 1056 words per channel
#define S1BUF (CCH*S1CH)     // 2304
#define S2BUF (CCH*S2CH)     // 4224
#define BUFSZ (S1BUF+S2BUF)  // 6528 words
#define NF4 1472             // float4s staged per chunk: 4*128 + 4*240
#define NSTG 3
#define CHSTRIDE (CCH*H_*W_) // 61440 floats

// __launch_bounds__(576, 1): one 9-wave block per CU. Worst-loaded SIMD
// carries 3 waves -> backend VGPR cap = 512/3 ~ 168, enough for the
// 72-reg accumulator tile + staging without spill.
// R1 (no bounds): assumed 1024-thr block, heuristic chose 84 VGPR -> spill.
// R2 (576,4): forced 2 blocks/CU co-residency -> 5 waves on a SIMD ->
// cap quantized to 64 VGPR -> worse spill (WRITE_SIZE 2.7 GB).
__global__ __launch_bounds__(NTHR, 1) void corr_kernel(
    const float* __restrict__ d1, const float* __restrict__ d2,
    float* __restrict__ out)
{
  __shared__ float sm[2*BUFSZ];   // 52,224 B
  const int tid = threadIdx.x;
  const int n  = blockIdx.z;
  const int y0 = blockIdx.y * TH;
  const int x0 = blockIdx.x * TW;

  // ---- staging precompute (per-thread constant across chunks) ----
  const float* gptr[NSTG];  // global source pointer (chunk 0)
  int   loff[NSTG];         // LDS word offset within buffer
  bool  pred[NSTG];         // issue the global load
  bool  wr[NSTG];           // issue the LDS write
  #pragma unroll
  for (int i = 0; i < NSTG; ++i) {
    int idx = tid + i*NTHR;
    bool valid = idx < NF4;
    bool inb = false; int go = 0, lo = 0; const float* sp = d1;
    if (idx < 512) {                 // data1 tile: 4c * 16r * 8 f4
      int c = idx >> 7, rem = idx & 127, r = rem >> 3, j = rem & 7;
      go = ((n*C_ + c)*H_ + (y0 + r))*W_ + (x0 + 4*j);
      lo = c*S1CH + r*S1STR + 4*j;
      inb = true; sp = d1;
    } else {                         // data2 halo tile: 4c * 24r * 10 f4
      int t = idx - 512;
      int c = t/240, rem = t%240, ry = rem/10, j = rem%10;
      int gy = y0 - 4 + ry, gx = x0 - 4 + 4*j;
      inb = (gy >= 0) & (gy < H_) & (gx >= 0) & (gx < W_); // f4 fully in or out
      go = ((n*C_ + c)*H_ + gy)*W_ + gx;
      lo = S1BUF + c*S2CH + ry*S2STR + 4*j;
      sp = d2;
    }
    gptr[i] = sp + go;
    loff[i] = lo;
    pred[i] = valid && inb;
    wr[i]   = valid;
  }

  float acc[9][PP];
  #pragma unroll
  for (int dx = 0; dx < 9; ++dx)
    #pragma unroll
    for (int p = 0; p < PP; ++p) acc[dx][p] = 0.f;

  const int g   = tid & (GROUPS-1);
  const int dy  = tid >> 6;          // 0..8, wave-uniform
  const int r   = g >> 2;            // tile row 0..15
  const int gx0 = (g & 3)*PP;        // tile col 0,8,16,24
  const int l1  = r*S1STR + gx0;
  const int l2  = S1BUF + (r + dy)*S2STR + gx0;

  float4 st[NSTG];

  auto load_chunk = [&](int k) {
    #pragma unroll
    for (int i = 0; i < NSTG; ++i) {
      float4 v = {0.f, 0.f, 0.f, 0.f};
      if (pred[i]) v = *(const float4*)(gptr[i] + (size_t)k*CHSTRIDE);
      st[i] = v;
    }
  };
  auto store_chunk = [&](int b) {
    float* dst = sm + b*BUFSZ;
    #pragma unroll
    for (int i = 0; i < NSTG; ++i)
      if (wr[i]) *(float4*)(dst + loff[i]) = st[i];
  };
  auto compute = [&](int b) {
    const float* base = sm + b*BUFSZ;
    #pragma unroll
    for (int c = 0; c < CCH; ++c) {
      const float* p1 = base + c*S1CH + l1;
      float4 A0 = *(const float4*)(p1);
      float4 A1 = *(const float4*)(p1 + 4);
      const float* p2 = base + c*S2CH + l2;
      float4 B0 = *(const float4*)(p2);
      float4 B1 = *(const float4*)(p2 + 4);
      float4 B2 = *(const float4*)(p2 + 8);
      float4 B3 = *(const float4*)(p2 + 12);
      float a1[8]  = {A0.x,A0.y,A0.z,A0.w,A1.x,A1.y,A1.z,A1.w};
      float a2[16] = {B0.x,B0.y,B0.z,B0.w,B1.x,B1.y,B1.z,B1.w,
                      B2.x,B2.y,B2.z,B2.w,B3.x,B3.y,B3.z,B3.w};
      #pragma unroll
      for (int dx = 0; dx < 9; ++dx)
        #pragma unroll
        for (int p = 0; p < PP; ++p)
          acc[dx][p] = fmaf(a1[p], a2[p+dx], acc[dx][p]);
    }
  };

  // ---- double-buffered main loop ----
  load_chunk(0);
  store_chunk(0);
  __syncthreads();
  #pragma unroll 1
  for (int k = 0; k < NCH-1; ++k) {
    load_chunk(k+1);        // global loads in flight during compute
    compute(k & 1);
    __syncthreads();        // all waves done reading buf[k&1]
    store_chunk((k+1) & 1);
    __syncthreads();        // writes visible
  }
  compute((NCH-1) & 1);

  // ---- epilogue ----
  const float scale = 1.0f/256.0f;
  const int y  = y0 + r;
  const int xb = x0 + gx0;
  #pragma unroll
  for (int dx = 0; dx < 9; ++dx) {
    int q = dy*9 + dx;
    size_t o = (((size_t)n*81 + q)*H_ + y)*W_ + xb;
    float4 lo4 = make_float4(acc[dx][0]*scale, acc[dx][1]*scale,
                             acc[dx][2]*scale, acc[dx][3]*scale);
    float4 hi4 = make_float4(acc[dx][4]*scale, acc[dx][5]*scale,
                             acc[dx][6]*scale, acc[dx][7]*scale);
    *(float4*)(out + o)     = lo4;
    *(float4*)(out + o + 4) = hi4;
  }
}

extern "C" void kernel_launch(void* const* d_in, const int* in_sizes, int n_in,
                              void* d_out, int out_size, void* d_ws, size_t ws_size,
                              hipStream_t stream) {
  const float* d1 = (const float*)d_in[0];
  const float* d2 = (const float*)d_in[1];
  float* out = (float*)d_out;
  dim3 grid(W_/TW, H_/TH, 8);  // 5 x 6 x 8 = 240 blocks
  corr_kernel<<<grid, NTHR, 0, stream>>>(d1, d2, out);
}

// Round 4
// 663.748 us; speedup vs baseline: 2.0758x; 1.0084x over previous
//
#include <hip/hip_runtime.h>
#include <cstdint>

#define C_ 256
#define H_ 96
#define W_ 160
#define TH 16
#define TW 32
#define PP 8
#define GROUPS 64            // (TH*TW)/PP
#define NTHR 576             // GROUPS * 9
#define CCH 4                // channels per chunk
#define NCH 64               // C_/CCH
#define S1STR 36             // padded row stride (words), tile row = 32
#define S2H 24               // TH + 8
#define S2W 40               // TW + 8
#define S2STR 44             // padded row stride (words)
#define S1CH (TH*S1STR)      // 576 words per channel
#define S2CH (S2H*S2STR)     // 1056 words per channel
#define S1BUF (CCH*S1CH)     // 2304
#define S2BUF (CCH*S2CH)     // 4224
#define BUFSZ (S1BUF+S2BUF)  // 6528 words
#define NF4 1472             // float4s staged per chunk: 4*128 + 4*240
#define NSTG 3
#define CHSTRIDE (CCH*H_*W_) // 61440 floats

// Register-budget control (R1-R3 saga):
//   R1/R3: allocator targets 6 waves/EU (LDS 52KB -> 3 blocks/CU -> 27
//   waves/CU -> 512/6 = 84 VGPRs) and spills ~22 regs -> 780 MB scratch
//   writes. __launch_bounds__ 2nd arg is only a MIN waves/EU; it cannot
//   lower the target. amdgpu_waves_per_eu(1,3) caps the target at 3
//   waves/EU -> budget 512/3 = 170 VGPRs, enough for acc[9][8] (72) +
//   staging (12) + addressing without spill. One 9-wave block/CU.
__global__
__attribute__((amdgpu_flat_work_group_size(NTHR, NTHR),
               amdgpu_waves_per_eu(1, 3)))
void corr_kernel(
    const float* __restrict__ d1, const float* __restrict__ d2,
    float* __restrict__ out)
{
  __shared__ float sm[2*BUFSZ];   // 52,224 B
  const int tid = threadIdx.x;
  const int n  = blockIdx.z;
  const int y0 = blockIdx.y * TH;
  const int x0 = blockIdx.x * TW;

  // ---- staging precompute (per-thread constant across chunks) ----
  const float* gptr[NSTG];  // global source pointer (chunk 0)
  int   loff[NSTG];         // LDS word offset within buffer
  bool  pred[NSTG];         // issue the global load
  bool  wr[NSTG];           // issue the LDS write
  #pragma unroll
  for (int i = 0; i < NSTG; ++i) {
    int idx = tid + i*NTHR;
    bool valid = idx < NF4;
    bool inb = false; int go = 0, lo = 0; const float* sp = d1;
    if (idx < 512) {                 // data1 tile: 4c * 16r * 8 f4
      int c = idx >> 7, rem = idx & 127, r = rem >> 3, j = rem & 7;
      go = ((n*C_ + c)*H_ + (y0 + r))*W_ + (x0 + 4*j);
      lo = c*S1CH + r*S1STR + 4*j;
      inb = true; sp = d1;
    } else {                         // data2 halo tile: 4c * 24r * 10 f4
      int t = idx - 512;
      int c = t/240, rem = t%240, ry = rem/10, j = rem%10;
      int gy = y0 - 4 + ry, gx = x0 - 4 + 4*j;
      inb = (gy >= 0) & (gy < H_) & (gx >= 0) & (gx < W_); // f4 fully in or out
      go = ((n*C_ + c)*H_ + gy)*W_ + gx;
      lo = S1BUF + c*S2CH + ry*S2STR + 4*j;
      sp = d2;
    }
    gptr[i] = sp + go;
    loff[i] = lo;
    pred[i] = valid && inb;
    wr[i]   = valid;
  }

  float acc[9][PP];
  #pragma unroll
  for (int dx = 0; dx < 9; ++dx)
    #pragma unroll
    for (int p = 0; p < PP; ++p) acc[dx][p] = 0.f;

  const int g   = tid & (GROUPS-1);
  const int dy  = tid >> 6;          // 0..8, wave-uniform
  const int r   = g >> 2;            // tile row 0..15
  const int gx0 = (g & 3)*PP;        // tile col 0,8,16,24
  const int l1  = r*S1STR + gx0;
  const int l2  = S1BUF + (r + dy)*S2STR + gx0;

  float4 st[NSTG];

  auto load_chunk = [&](int k) {
    #pragma unroll
    for (int i = 0; i < NSTG; ++i) {
      float4 v = {0.f, 0.f, 0.f, 0.f};
      if (pred[i]) v = *(const float4*)(gptr[i] + (size_t)k*CHSTRIDE);
      st[i] = v;
    }
  };
  auto store_chunk = [&](int b) {
    float* dst = sm + b*BUFSZ;
    #pragma unroll
    for (int i = 0; i < NSTG; ++i)
      if (wr[i]) *(float4*)(dst + loff[i]) = st[i];
  };
  auto compute = [&](int b) {
    const float* base = sm + b*BUFSZ;
    #pragma unroll
    for (int c = 0; c < CCH; ++c) {
      const float* p1 = base + c*S1CH + l1;
      float4 A0 = *(const float4*)(p1);
      float4 A1 = *(const float4*)(p1 + 4);
      const float* p2 = base + c*S2CH + l2;
      float4 B0 = *(const float4*)(p2);
      float4 B1 = *(const float4*)(p2 + 4);
      float4 B2 = *(const float4*)(p2 + 8);
      float4 B3 = *(const float4*)(p2 + 12);
      float a1[8]  = {A0.x,A0.y,A0.z,A0.w,A1.x,A1.y,A1.z,A1.w};
      float a2[16] = {B0.x,B0.y,B0.z,B0.w,B1.x,B1.y,B1.z,B1.w,
                      B2.x,B2.y,B2.z,B2.w,B3.x,B3.y,B3.z,B3.w};
      #pragma unroll
      for (int dx = 0; dx < 9; ++dx)
        #pragma unroll
        for (int p = 0; p < PP; ++p)
          acc[dx][p] = fmaf(a1[p], a2[p+dx], acc[dx][p]);
    }
  };

  // ---- double-buffered main loop ----
  load_chunk(0);
  store_chunk(0);
  __syncthreads();
  #pragma unroll 1
  for (int k = 0; k < NCH-1; ++k) {
    load_chunk(k+1);        // global loads in flight during compute
    compute(k & 1);
    __syncthreads();        // all waves done reading buf[k&1]
    store_chunk((k+1) & 1);
    __syncthreads();        // writes visible
  }
  compute((NCH-1) & 1);

  // ---- epilogue ----
  const float scale = 1.0f/256.0f;
  const int y  = y0 + r;
  const int xb = x0 + gx0;
  #pragma unroll
  for (int dx = 0; dx < 9; ++dx) {
    int q = dy*9 + dx;
    size_t o = (((size_t)n*81 + q)*H_ + y)*W_ + xb;
    float4 lo4 = make_float4(acc[dx][0]*scale, acc[dx][1]*scale,
                             acc[dx][2]*scale, acc[dx][3]*scale);
    float4 hi4 = make_float4(acc[dx][4]*scale, acc[dx][5]*scale,
                             acc[dx][6]*scale, acc[dx][7]*scale);
    *(float4*)(out + o)     = lo4;
    *(float4*)(out + o + 4) = hi4;
  }
}

extern "C" void kernel_launch(void* const* d_in, const int* in_sizes, int n_in,
                              void* d_out, int out_size, void* d_ws, size_t ws_size,
                              hipStream_t stream) {
  const float* d1 = (const float*)d_in[0];
  const float* d2 = (const float*)d_in[1];
  float* out = (float*)d_out;
  dim3 grid(W_/TW, H_/TH, 8);  // 5 x 6 x 8 = 240 blocks
  corr_kernel<<<grid, NTHR, 0, stream>>>(d1, d2, out);
}